// Round 3
// baseline (999.642 us; speedup 1.0000x reference)
//
#include <hip/hip_runtime.h>

// ---------------- problem constants ----------------
#define NN 50000
#define EE 800000
// HID=128, EDGE_DIM=16, HEADS=4, C=32

// ---------------- ws layout (4-byte element offsets) ----------------
// Aliasing: gat reuses xr (dead after k2a); h reuses xl (dead after k2c).
#define OFF_XL  0u          // N*128 floats  (later: h)
#define OFF_XR  6400000u    // N*128 floats  (later: gat)
#define OFF_LG  12800000u   // E*4 floats
#define OFF_CNT 16000000u   // N ints
#define OFF_OFS 16050000u   // N+1 ints
#define OFF_POS 16100001u   // N ints
#define OFF_EID 16150001u   // E ints
// total ~16.95M elems ≈ 68 MB of ws

#define FFN_BLOCKS 2048
#define RMS_EPS 1.1920928955078125e-7f

__device__ __forceinline__ float readlane_f32(float v, int lane) {
  return __int_as_float(__builtin_amdgcn_readlane(__float_as_int(v), lane));
}
__device__ __forceinline__ int readlane_i32(int v, int lane) {
  return __builtin_amdgcn_readlane(v, lane);
}

// ---------------- small utility kernels ----------------
__global__ __launch_bounds__(256) void k_zero(int* __restrict__ p, int n) {
  int i = blockIdx.x * 256 + threadIdx.x;
  if (i < n) p[i] = 0;
}

// ---------------- K1: xl = x@Wl+bl, xr = x@Wr+br (fp32 out) ----------------
__global__ __launch_bounds__(256) void k1_xlr(const float* __restrict__ x,
    const float* __restrict__ Wl, const float* __restrict__ Wr,
    const float* __restrict__ bl, const float* __restrict__ br,
    float* __restrict__ xl, float* __restrict__ xr)
{
  int tid = threadIdx.x;
  int jj = tid & 127;
  bool isR = tid >= 128;
  const float* Wf = isR ? Wr : Wl;
  float bias = isR ? br[jj] : bl[jj];
  float* dbase = isR ? xr : xl;
  for (int tile = blockIdx.x; tile < NN / 8; tile += gridDim.x) {
    int row0 = tile * 8;
    float acc[8];
#pragma unroll
    for (int r = 0; r < 8; ++r) acc[r] = 0.f;
    const float* xb = x + row0 * 128;
    for (int k4 = 0; k4 < 128; k4 += 4) {
      float4 xv[8];
#pragma unroll
      for (int r = 0; r < 8; ++r) xv[r] = *(const float4*)(xb + r * 128 + k4);
#pragma unroll
      for (int kk = 0; kk < 4; ++kk) {
        float wv = Wf[(k4 + kk) * 128 + jj];
#pragma unroll
        for (int r = 0; r < 8; ++r) acc[r] = fmaf((&xv[r].x)[kk], wv, acc[r]);
      }
    }
    float* dst = dbase + row0 * 128 + jj;
#pragma unroll
    for (int r = 0; r < 8; ++r) dst[r * 128] = acc[r] + bias;
  }
}

// ---------------- K2a: per-edge logits (wave per edge) ----------------
__global__ __launch_bounds__(256) void k2a_logits(
    const int* __restrict__ ei, const float* __restrict__ eattr,
    const float* __restrict__ att, const float* __restrict__ We,
    const float* __restrict__ xl, const float* __restrict__ xr,
    float* __restrict__ logits)
{
  int l = threadIdx.x & 63;
  int wid = (blockIdx.x * blockDim.x + threadIdx.x) >> 6;
  int nw = (gridDim.x * blockDim.x) >> 6;
  const float2* We2 = (const float2*)We;   // [16][64] as float2: cols 2l,2l+1
  float2 wef[16];
#pragma unroll
  for (int k = 0; k < 16; ++k) wef[k] = We2[k * 64 + l];
  float a0 = att[2 * l], a1 = att[2 * l + 1];
  for (int e = wid; e < EE; e += nw) {
    int src = ei[e];
    int dst = ei[EE + e];
    float eav = 0.f;
    if (l < 16) eav = eattr[e * 16 + l];
    float ep0 = 0.f, ep1 = 0.f;
#pragma unroll
    for (int k = 0; k < 16; ++k) {
      float ek = readlane_f32(eav, k);
      ep0 = fmaf(ek, wef[k].x, ep0);
      ep1 = fmaf(ek, wef[k].y, ep1);
    }
    float2 xlv = *(const float2*)(xl + src * 128 + 2 * l);
    float2 xrv = *(const float2*)(xr + dst * 128 + 2 * l);
    float m0 = xlv.x + xrv.x + ep0;
    float m1 = xlv.y + xrv.y + ep1;
    float s0 = m0 > 0.f ? m0 : 0.2f * m0;   // LeakyReLU(0.2)
    float s1 = m1 > 0.f ? m1 : 0.2f * m1;
    float p = fmaf(s0, a0, s1 * a1);
    // reduce within 16-lane head groups
    p += __shfl_xor(p, 1); p += __shfl_xor(p, 2);
    p += __shfl_xor(p, 4); p += __shfl_xor(p, 8);
    if ((l & 15) == 0) logits[e * 4 + (l >> 4)] = p;
  }
}

// ---------------- CSR build ----------------
__global__ __launch_bounds__(256) void k_hist(const int* __restrict__ ei, int* __restrict__ cnt) {
  int e = blockIdx.x * 256 + threadIdx.x;
  if (e < EE) atomicAdd(&cnt[ei[EE + e]], 1);
}

__global__ __launch_bounds__(1024) void k_scan(const int* __restrict__ cnt,
    int* __restrict__ offs, int* __restrict__ pos)
{
  __shared__ int buf[1024];
  __shared__ int carry_s;
  int tid = threadIdx.x;
  if (tid == 0) carry_s = 0;
  __syncthreads();
  for (int base = 0; base < NN; base += 1024) {
    int i = base + tid;
    int v = (i < NN) ? cnt[i] : 0;
    buf[tid] = v;
    __syncthreads();
    int x = v;
    for (int ofs = 1; ofs < 1024; ofs <<= 1) {
      int y = (tid >= ofs) ? buf[tid - ofs] : 0;
      __syncthreads();
      x += y;
      buf[tid] = x;
      __syncthreads();
    }
    int carry = carry_s;
    int incl = x + carry;
    if (i < NN) { offs[i + 1] = incl; pos[i] = incl - v; }
    if (tid == 0 && base == 0) offs[0] = 0;
    __syncthreads();
    if (tid == 1023) carry_s = incl;
    __syncthreads();
  }
}

__global__ __launch_bounds__(256) void k_scatter(const int* __restrict__ ei,
    int* __restrict__ pos, int* __restrict__ eidarr)
{
  int e = blockIdx.x * 256 + threadIdx.x;
  if (e < EE) {
    int slot = atomicAdd(&pos[ei[EE + e]], 1);
    eidarr[slot] = e;
  }
}

// ---------------- K2c: per-dst softmax + weighted accumulation (wave per dst) ----------------
__global__ __launch_bounds__(256) void k2c_attn(
    const int* __restrict__ ei, const int* __restrict__ offs,
    const int* __restrict__ eidarr, const float* __restrict__ logits,
    const float* __restrict__ xl, float* __restrict__ gat)
{
  int l = threadIdx.x & 63;
  int wid = (blockIdx.x * blockDim.x + threadIdx.x) >> 6;
  int nw = (gridDim.x * blockDim.x) >> 6;
  int hh = l >> 4;
  int c0 = 2 * l;
  const float4* lg4 = (const float4*)logits;
  for (int d = wid; d < NN; d += nw) {
    int start = offs[d];
    int deg = offs[d + 1] - start;
    float4 mx = make_float4(-__builtin_inff(), -__builtin_inff(), -__builtin_inff(), -__builtin_inff());
    for (int i = l; i < deg; i += 64) {
      float4 g = lg4[eidarr[start + i]];
      mx.x = fmaxf(mx.x, g.x); mx.y = fmaxf(mx.y, g.y);
      mx.z = fmaxf(mx.z, g.z); mx.w = fmaxf(mx.w, g.w);
    }
#pragma unroll
    for (int o = 1; o < 64; o <<= 1) {
      mx.x = fmaxf(mx.x, __shfl_xor(mx.x, o));
      mx.y = fmaxf(mx.y, __shfl_xor(mx.y, o));
      mx.z = fmaxf(mx.z, __shfl_xor(mx.z, o));
      mx.w = fmaxf(mx.w, __shfl_xor(mx.w, o));
    }
    float4 sm = make_float4(0.f, 0.f, 0.f, 0.f);
    for (int i = l; i < deg; i += 64) {
      float4 g = lg4[eidarr[start + i]];
      sm.x += expf(g.x - mx.x); sm.y += expf(g.y - mx.y);
      sm.z += expf(g.z - mx.z); sm.w += expf(g.w - mx.w);
    }
#pragma unroll
    for (int o = 1; o < 64; o <<= 1) {
      sm.x += __shfl_xor(sm.x, o); sm.y += __shfl_xor(sm.y, o);
      sm.z += __shfl_xor(sm.z, o); sm.w += __shfl_xor(sm.w, o);
    }
    float mh = hh == 0 ? mx.x : hh == 1 ? mx.y : hh == 2 ? mx.z : mx.w;
    float dh = hh == 0 ? sm.x : hh == 1 ? sm.y : hh == 2 ? sm.z : sm.w;
    float idh = 1.f / (dh + 1e-16f);
    float acc0 = 0.f, acc1 = 0.f;
    for (int base = 0; base < deg; base += 64) {
      int eidv = 0, srcv = 0;
      if (base + l < deg) { eidv = eidarr[start + base + l]; srcv = ei[eidv]; }
      int cnt = min(64, deg - base);
      for (int j = 0; j < cnt; ++j) {
        int eid = readlane_i32(eidv, j);
        int sr  = readlane_i32(srcv, j);
        float lgh = logits[eid * 4 + hh];
        float a = expf(lgh - mh) * idh;
        float2 xv = *(const float2*)(xl + sr * 128 + c0);
        acc0 = fmaf(a, xv.x, acc0);
        acc1 = fmaf(a, xv.y, acc1);
      }
    }
    *(float2*)(gat + d * 128 + c0) = make_float2(acc0, acc1);
  }
}

// ---------------- K5: h = rmsnorm(x + gat + bias_gat, w_norm1) ----------------
__global__ __launch_bounds__(256) void k5_norm1(const float* __restrict__ x,
    const float* __restrict__ gat, const float* __restrict__ bg,
    const float* __restrict__ wn1, float* __restrict__ h)
{
  int l = threadIdx.x & 63;
  int row = blockIdx.x * 4 + (threadIdx.x >> 6);
  int c0 = 2 * l;
  float2 xu = *(const float2*)(x + row * 128 + c0);
  float2 gv = *(const float2*)(gat + row * 128 + c0);
  float2 bu = *(const float2*)(bg + c0);
  float v0 = xu.x + gv.x + bu.x;
  float v1 = xu.y + gv.y + bu.y;
  float ss = v0 * v0 + v1 * v1;
#pragma unroll
  for (int o = 1; o < 64; o <<= 1) ss += __shfl_xor(ss, o);
  float rr = rsqrtf(ss * (1.f / 128.f) + RMS_EPS);
  float2 wu = *(const float2*)(wn1 + c0);
  *(float2*)(h + row * 128 + c0) = make_float2(v0 * rr * wu.x, v1 * rr * wu.y);
}

// ---------------- K6: fused FFN + residual + rmsnorm2, fp32 out, LDS scratch ----------------
__global__ __launch_bounds__(256) void k6_ffn(const float* __restrict__ h,
    const float* __restrict__ W1, const float* __restrict__ W2,
    const float* __restrict__ b1, const float* __restrict__ b2,
    const float* __restrict__ wn2, float* __restrict__ out)
{
  __shared__ float tslot[8 * 512];   // 16 KB
  __shared__ float red[4][4];
  int tid = threadIdx.x;
  int l = tid & 63, w = tid >> 6;
  int c = tid & 127, rg = tid >> 7;
  float bb0 = b1[tid], bb1 = b1[tid + 256];
  float bb2 = b2[c];
  float wno = wn2[c];
  for (int tile = blockIdx.x; tile < NN / 8; tile += gridDim.x) {
    int row0 = tile * 8;
    const float* hb = h + row0 * 128;
    float acc[8][2];
#pragma unroll
    for (int r = 0; r < 8; ++r) { acc[r][0] = 0.f; acc[r][1] = 0.f; }
    for (int k4 = 0; k4 < 128; k4 += 4) {
      float4 hv[8];
#pragma unroll
      for (int r = 0; r < 8; ++r) hv[r] = *(const float4*)(hb + r * 128 + k4);
#pragma unroll
      for (int kk = 0; kk < 4; ++kk) {
        float w0 = W1[(k4 + kk) * 512 + tid];
        float w1 = W1[(k4 + kk) * 512 + tid + 256];
#pragma unroll
        for (int r = 0; r < 8; ++r) {
          float hvv = (&hv[r].x)[kk];
          acc[r][0] = fmaf(hvv, w0, acc[r][0]);
          acc[r][1] = fmaf(hvv, w1, acc[r][1]);
        }
      }
    }
#pragma unroll
    for (int r = 0; r < 8; ++r) {
      float t0 = acc[r][0] + bb0, t1 = acc[r][1] + bb1;
      t0 = 0.5f * t0 * (1.f + erff(t0 * 0.70710678118654752f));   // exact GELU
      t1 = 0.5f * t1 * (1.f + erff(t1 * 0.70710678118654752f));
      tslot[r * 512 + tid] = t0;
      tslot[r * 512 + tid + 256] = t1;
    }
    __syncthreads();
    float f[4] = {0.f, 0.f, 0.f, 0.f};
    for (int j4 = 0; j4 < 512; j4 += 4) {
      float4 tv[4];
#pragma unroll
      for (int r = 0; r < 4; ++r) tv[r] = *(const float4*)(tslot + (rg * 4 + r) * 512 + j4);
#pragma unroll
      for (int kk = 0; kk < 4; ++kk) {
        float wv = W2[(j4 + kk) * 128 + c];
#pragma unroll
        for (int r = 0; r < 4; ++r) f[r] = fmaf((&tv[r].x)[kk], wv, f[r]);
      }
    }
    float ov[4], ssq[4];
#pragma unroll
    for (int r = 0; r < 4; ++r) {
      int row = row0 + rg * 4 + r;
      ov[r] = h[row * 128 + c] + f[r] + bb2;
      float s = ov[r] * ov[r];
#pragma unroll
      for (int o = 1; o < 64; o <<= 1) s += __shfl_xor(s, o);
      ssq[r] = s;
    }
    if (l == 0) {
#pragma unroll
      for (int r = 0; r < 4; ++r) red[w][r] = ssq[r];
    }
    __syncthreads();
#pragma unroll
    for (int r = 0; r < 4; ++r) {
      float tot = red[rg * 2][r] + red[rg * 2 + 1][r];
      float rr = rsqrtf(tot * (1.f / 128.f) + RMS_EPS);
      int row = row0 + rg * 4 + r;
      out[row * 128 + c] = ov[r] * rr * wno;
    }
    __syncthreads();
  }
}

// ---------------- launch ----------------
extern "C" void kernel_launch(void* const* d_in, const int* in_sizes, int n_in,
                              void* d_out, int out_size, void* d_ws, size_t ws_size,
                              hipStream_t stream) {
  const float* x   = (const float*)d_in[0];
  const int*   ei  = (const int*)d_in[1];
  const float* ea  = (const float*)d_in[2];
  const float* Wl  = (const float*)d_in[3];
  const float* bl  = (const float*)d_in[4];
  const float* Wr  = (const float*)d_in[5];
  const float* br  = (const float*)d_in[6];
  const float* We  = (const float*)d_in[7];
  const float* att = (const float*)d_in[8];
  const float* bg  = (const float*)d_in[9];
  const float* wn1 = (const float*)d_in[10];
  const float* wn2 = (const float*)d_in[11];
  const float* W1  = (const float*)d_in[12];
  const float* b1  = (const float*)d_in[13];
  const float* W2  = (const float*)d_in[14];
  const float* b2  = (const float*)d_in[15];

  float* wsf = (float*)d_ws;
  int*   wsi = (int*)d_ws;

  float* xl   = wsf + OFF_XL;
  float* xr   = wsf + OFF_XR;
  float* gat  = wsf + OFF_XR;   // aliases xr (dead after k2a)
  float* hbuf = wsf + OFF_XL;   // aliases xl (dead after k2c)
  float* lg   = wsf + OFF_LG;
  int* cnt    = wsi + OFF_CNT;
  int* offs   = wsi + OFF_OFS;
  int* pos    = wsi + OFF_POS;
  int* eidarr = wsi + OFF_EID;

  k_zero<<<(NN + 255) / 256, 256, 0, stream>>>(cnt, NN);
  k1_xlr<<<2048, 256, 0, stream>>>(x, Wl, Wr, bl, br, xl, xr);
  k2a_logits<<<1024, 256, 0, stream>>>(ei, ea, att, We, xl, xr, lg);

  k_hist<<<(EE + 255) / 256, 256, 0, stream>>>(ei, cnt);
  k_scan<<<1, 1024, 0, stream>>>(cnt, offs, pos);
  k_scatter<<<(EE + 255) / 256, 256, 0, stream>>>(ei, pos, eidarr);

  k2c_attn<<<1024, 256, 0, stream>>>(ei, offs, eidarr, lg, xl, gat);
  k5_norm1<<<NN / 4, 256, 0, stream>>>(x, gat, bg, wn1, hbuf);
  k6_ffn<<<FFN_BLOCKS, 256, 0, stream>>>(hbuf, W1, W2, b1, b2, wn2, (float*)d_out);
}

// Round 5
// 766.861 us; speedup vs baseline: 1.3036x; 1.3036x over previous
//
#include <hip/hip_runtime.h>

// ---------------- problem constants ----------------
#define NN 50000
#define EE 800000
// HID=128, EDGE_DIM=16, HEADS=4, C=32

typedef unsigned short u16;

// ---------------- ws layout (4-byte element offsets), total 67.93 MB ----------------
#define OFF_XL   0u          // N*128 f32 (later: h)
#define OFF_XR   6400000u    // N*128 f32 (later: gat)
#define OFF_LGP  12800000u   // E*4 f32 (CSR-ordered logits)
#define OFF_WLRT 16000000u   // 256x128 bf16 (16384 f32 slots)
#define OFF_W1T  16016384u   // 512x128 bf16 (32768)
#define OFF_W2T  16049152u   // 128x512 bf16 (32768)
#define OFF_CNT  16081920u   // N ints; after k_scan holds CSR cursors (pos)
#define OFF_OFS  16131920u   // N+1 ints (pristine CSR offsets)
#define OFF_SRC  16181921u   // E ints (CSR-ordered src)
// end: 16981921 f32 = 67,927,684 bytes

#define RMS_EPS 1.1920928955078125e-7f

typedef float f32x4v __attribute__((ext_vector_type(4)));
typedef short s16x8 __attribute__((ext_vector_type(8)));

__device__ __forceinline__ f32x4v mfma16(s16x8 a, s16x8 b, f32x4v c) {
  return __builtin_amdgcn_mfma_f32_16x16x32_bf16(a, b, c, 0, 0, 0);
}
__device__ __forceinline__ u16 f2b(float f) {
  unsigned int u = __float_as_uint(f);
  unsigned int r = (u + 0x7fffu + ((u >> 16) & 1u)) >> 16;
  return (u16)r;
}
// load 8 fp32, convert to bf16 fragment in-register
__device__ __forceinline__ s16x8 ld_bf16x8_f32(const float* __restrict__ p) {
  float4 v0 = *(const float4*)p;
  float4 v1 = *(const float4*)(p + 4);
  s16x8 r;
  r[0] = (short)f2b(v0.x); r[1] = (short)f2b(v0.y);
  r[2] = (short)f2b(v0.z); r[3] = (short)f2b(v0.w);
  r[4] = (short)f2b(v1.x); r[5] = (short)f2b(v1.y);
  r[6] = (short)f2b(v1.z); r[7] = (short)f2b(v1.w);
  return r;
}
__device__ __forceinline__ float readlane_f32(float v, int lane) {
  return __int_as_float(__builtin_amdgcn_readlane(__float_as_int(v), lane));
}
__device__ __forceinline__ int readlane_i32(int v, int lane) {
  return __builtin_amdgcn_readlane(v, lane);
}

// ---------------- utility kernels ----------------
__global__ __launch_bounds__(256) void k_zero(int* __restrict__ p, int n) {
  int i = blockIdx.x * 256 + threadIdx.x;
  if (i < n) p[i] = 0;
}
// Wlrt[n*128+k] = bf16( n<128 ? Wl[k][n] : Wr[k][n-128] ), n in [0,256)
__global__ __launch_bounds__(256) void k_tcvt2(const float* __restrict__ Wl, const float* __restrict__ Wr,
                                               u16* __restrict__ out) {
  int i = blockIdx.x * 256 + threadIdx.x;  // 32768
  int n = i >> 7, k = i & 127;
  float v = (n < 128) ? Wl[k * 128 + n] : Wr[k * 128 + (n - 128)];
  out[i] = f2b(v);
}
// W1t[n*128+k] = bf16(W1[k*512+n]), n in [0,512)
__global__ __launch_bounds__(256) void k_t1(const float* __restrict__ W1, u16* __restrict__ out) {
  int i = blockIdx.x * 256 + threadIdx.x;  // 65536
  int n = i >> 7, k = i & 127;
  out[i] = f2b(W1[k * 512 + n]);
}
// W2t[n*512+k] = bf16(W2[k*128+n]), n in [0,128), k in [0,512)
__global__ __launch_bounds__(256) void k_t2(const float* __restrict__ W2, u16* __restrict__ out) {
  int i = blockIdx.x * 256 + threadIdx.x;  // 65536
  int n = i >> 9, k = i & 511;
  out[i] = f2b(W2[k * 128 + n]);
}

// ---------------- CSR build (runs BEFORE k2a) ----------------
__global__ __launch_bounds__(256) void k_hist(const int* __restrict__ ei, int* __restrict__ cnt) {
  int e = blockIdx.x * 256 + threadIdx.x;
  if (e < EE) atomicAdd(&cnt[ei[EE + e]], 1);
}

// scan: offs = exclusive-prefix (N+1); pos (aliases cnt) = cursor copy of offs[0..N)
__global__ __launch_bounds__(1024) void k_scan(const int* __restrict__ cnt,
    int* __restrict__ offs, int* __restrict__ pos)
{
  __shared__ int wsum[16];
  __shared__ int carry_s;
  int tid = threadIdx.x, lane = tid & 63, wv = tid >> 6;
  if (tid == 0) carry_s = 0;
  __syncthreads();
  for (int base = 0; base < NN; base += 1024) {
    int i = base + tid;
    int v = (i < NN) ? cnt[i] : 0;
    int x = v;
#pragma unroll
    for (int ofs = 1; ofs < 64; ofs <<= 1) {
      int y = __shfl_up(x, ofs);
      if (lane >= ofs) x += y;
    }
    if (lane == 63) wsum[wv] = x;
    __syncthreads();
    if (wv == 0) {
      int s = (lane < 16) ? wsum[lane] : 0;
#pragma unroll
      for (int ofs = 1; ofs < 16; ofs <<= 1) {
        int y = __shfl_up(s, ofs);
        if (lane >= ofs) s += y;
      }
      if (lane < 16) wsum[lane] = s;
    }
    __syncthreads();
    int wbase = (wv > 0) ? wsum[wv - 1] : 0;
    int incl = x + wbase + carry_s;
    if (i < NN) { offs[i + 1] = incl; pos[i] = incl - v; }
    if (base == 0 && tid == 0) offs[0] = 0;
    __syncthreads();
    if (tid == 1023) carry_s = incl;
    __syncthreads();
  }
}

// ---------------- K1: [xl|xr] = x @ [Wl|Wr] + [bl|br], bf16 MFMA, fp32 src ----------------
__global__ __launch_bounds__(256) void k1_mfma(const float* __restrict__ x, const u16* __restrict__ wlrt,
    const float* __restrict__ bl, const float* __restrict__ br,
    float* __restrict__ xl, float* __restrict__ xr)
{
  int tid = threadIdx.x;
  int w = tid >> 6, lane = tid & 63;
  int quad = lane >> 4, l16 = lane & 15;
  int row0 = blockIdx.x * 32;
  int ko = quad * 8;
  f32x4v acc[2][4];
#pragma unroll
  for (int mt = 0; mt < 2; ++mt)
#pragma unroll
    for (int nt = 0; nt < 4; ++nt) acc[mt][nt] = (f32x4v){0.f, 0.f, 0.f, 0.f};
#pragma unroll
  for (int ks = 0; ks < 4; ++ks) {
    int k0 = ks * 32 + ko;
    s16x8 a[2];
#pragma unroll
    for (int mt = 0; mt < 2; ++mt) {
      int row = row0 + mt * 16 + l16; if (row >= NN) row = NN - 1;
      a[mt] = ld_bf16x8_f32(x + row * 128 + k0);
    }
#pragma unroll
    for (int nt = 0; nt < 4; ++nt) {
      int col = w * 64 + nt * 16 + l16;
      s16x8 b = *(const s16x8*)(wlrt + col * 128 + k0);
      acc[0][nt] = mfma16(a[0], b, acc[0][nt]);
      acc[1][nt] = mfma16(a[1], b, acc[1][nt]);
    }
  }
#pragma unroll
  for (int nt = 0; nt < 4; ++nt) {
    int col = w * 64 + nt * 16 + l16;
    bool isl = col < 128;
    float bias = isl ? bl[col] : br[col - 128];
    float* dst = isl ? xl : xr;
    int cc = isl ? col : col - 128;
#pragma unroll
    for (int mt = 0; mt < 2; ++mt)
#pragma unroll
      for (int r = 0; r < 4; ++r) {
        int row = row0 + mt * 16 + quad * 4 + r;
        if (row < NN) dst[row * 128 + cc] = acc[mt][nt][r] + bias;
      }
  }
}

// ---------------- K2a: per-edge logits, fused CSR scatter (wave per edge) ----------------
__global__ __launch_bounds__(256) void k2a_logits(
    const int* __restrict__ ei, const float* __restrict__ eattr,
    const float* __restrict__ att, const float* __restrict__ We,
    const float* __restrict__ xl, const float* __restrict__ xr,
    int* __restrict__ pos, int* __restrict__ srcarr, float* __restrict__ lgp)
{
  int l = threadIdx.x & 63;
  int wid = (blockIdx.x * blockDim.x + threadIdx.x) >> 6;
  int nw = (gridDim.x * blockDim.x) >> 6;
  const float2* We2 = (const float2*)We;   // [16][64] float2: cols 2l,2l+1
  float2 wef[16];
#pragma unroll
  for (int k = 0; k < 16; ++k) wef[k] = We2[k * 64 + l];
  float a0 = att[2 * l], a1 = att[2 * l + 1];
  for (int e = wid; e < EE; e += nw) {
    int src = ei[e];
    int dst = ei[EE + e];
    float eav = 0.f;
    if (l < 16) eav = eattr[e * 16 + l];
    float ep0 = 0.f, ep1 = 0.f;
#pragma unroll
    for (int k = 0; k < 16; ++k) {
      float ek = readlane_f32(eav, k);
      ep0 = fmaf(ek, wef[k].x, ep0);
      ep1 = fmaf(ek, wef[k].y, ep1);
    }
    float2 xlv = *(const float2*)(xl + src * 128 + 2 * l);
    float2 xrv = *(const float2*)(xr + dst * 128 + 2 * l);
    float m0 = xlv.x + xrv.x + ep0;
    float m1 = xlv.y + xrv.y + ep1;
    float s0 = m0 > 0.f ? m0 : 0.2f * m0;   // LeakyReLU(0.2)
    float s1 = m1 > 0.f ? m1 : 0.2f * m1;
    float p = fmaf(s0, a0, s1 * a1);
    p += __shfl_xor(p, 1); p += __shfl_xor(p, 2);
    p += __shfl_xor(p, 4); p += __shfl_xor(p, 8);
    // claim CSR slot, write logits + src in CSR order
    int slot = 0;
    if (l == 0) slot = atomicAdd(&pos[dst], 1);
    slot = __shfl(slot, 0);
    if (l == 0) srcarr[slot] = src;
    if ((l & 15) == 0) lgp[slot * 4 + (l >> 4)] = p;
  }
}

// ---------------- K2c: per-dst softmax + weighted accumulation (wave per dst) ----------------
__global__ __launch_bounds__(256) void k2c_attn(
    const int* __restrict__ offs, const int* __restrict__ srcarr,
    const float* __restrict__ lgp, const float* __restrict__ xl,
    float* __restrict__ gat)
{
  int l = threadIdx.x & 63;
  int wid = (blockIdx.x * blockDim.x + threadIdx.x) >> 6;
  int nw = (gridDim.x * blockDim.x) >> 6;
  int hh = l >> 4;
  int c0 = 2 * l;
  const float4* lg4 = (const float4*)lgp;
  for (int d = wid; d < NN; d += nw) {
    int start = offs[d];
    int deg = offs[d + 1] - start;
    float4 mx = make_float4(-__builtin_inff(), -__builtin_inff(), -__builtin_inff(), -__builtin_inff());
    for (int i = l; i < deg; i += 64) {
      float4 g = lg4[start + i];
      mx.x = fmaxf(mx.x, g.x); mx.y = fmaxf(mx.y, g.y);
      mx.z = fmaxf(mx.z, g.z); mx.w = fmaxf(mx.w, g.w);
    }
#pragma unroll
    for (int o = 1; o < 64; o <<= 1) {
      mx.x = fmaxf(mx.x, __shfl_xor(mx.x, o));
      mx.y = fmaxf(mx.y, __shfl_xor(mx.y, o));
      mx.z = fmaxf(mx.z, __shfl_xor(mx.z, o));
      mx.w = fmaxf(mx.w, __shfl_xor(mx.w, o));
    }
    float4 sm = make_float4(0.f, 0.f, 0.f, 0.f);
    for (int i = l; i < deg; i += 64) {
      float4 g = lg4[start + i];
      sm.x += __expf(g.x - mx.x); sm.y += __expf(g.y - mx.y);
      sm.z += __expf(g.z - mx.z); sm.w += __expf(g.w - mx.w);
    }
#pragma unroll
    for (int o = 1; o < 64; o <<= 1) {
      sm.x += __shfl_xor(sm.x, o); sm.y += __shfl_xor(sm.y, o);
      sm.z += __shfl_xor(sm.z, o); sm.w += __shfl_xor(sm.w, o);
    }
    float4 iv = make_float4(1.f / (sm.x + 1e-16f), 1.f / (sm.y + 1e-16f),
                            1.f / (sm.z + 1e-16f), 1.f / (sm.w + 1e-16f));
    float acc0 = 0.f, acc1 = 0.f;
    for (int base = 0; base < deg; base += 64) {
      int idx = start + base + l;
      bool act = (base + l) < deg;
      int srcv = act ? srcarr[idx] : 0;
      float4 g = act ? lg4[idx] : make_float4(0.f, 0.f, 0.f, 0.f);
      float4 av = make_float4(__expf(g.x - mx.x) * iv.x, __expf(g.y - mx.y) * iv.y,
                              __expf(g.z - mx.z) * iv.z, __expf(g.w - mx.w) * iv.w);
      int cnt = min(64, deg - base);
      for (int j = 0; j < cnt; ++j) {
        int sr = readlane_i32(srcv, j);
        float a0 = readlane_f32(av.x, j);
        float a1 = readlane_f32(av.y, j);
        float a2 = readlane_f32(av.z, j);
        float a3 = readlane_f32(av.w, j);
        float a = hh == 0 ? a0 : hh == 1 ? a1 : hh == 2 ? a2 : a3;
        float2 xv = *(const float2*)(xl + sr * 128 + c0);
        acc0 = fmaf(a, xv.x, acc0);
        acc1 = fmaf(a, xv.y, acc1);
      }
    }
    *(float2*)(gat + d * 128 + c0) = make_float2(acc0, acc1);
  }
}

// ---------------- K5: h = rmsnorm(x + gat + bias_gat, w_norm1) ----------------
__global__ __launch_bounds__(256) void k5_norm1(const float* __restrict__ x,
    const float* __restrict__ gat, const float* __restrict__ bg,
    const float* __restrict__ wn1, float* __restrict__ h)
{
  int l = threadIdx.x & 63;
  int row = blockIdx.x * 4 + (threadIdx.x >> 6);
  int c0 = 2 * l;
  float2 xu = *(const float2*)(x + row * 128 + c0);
  float2 gv = *(const float2*)(gat + row * 128 + c0);
  float2 bu = *(const float2*)(bg + c0);
  float v0 = xu.x + gv.x + bu.x;
  float v1 = xu.y + gv.y + bu.y;
  float ss = v0 * v0 + v1 * v1;
#pragma unroll
  for (int o = 1; o < 64; o <<= 1) ss += __shfl_xor(ss, o);
  float rr = rsqrtf(ss * (1.f / 128.f) + RMS_EPS);
  float2 wu = *(const float2*)(wn1 + c0);
  *(float2*)(h + row * 128 + c0) = make_float2(v0 * rr * wu.x, v1 * rr * wu.y);
}

// ---------------- K6: fused FFN (bf16 MFMA, fp32 src) + residual + rmsnorm2 ----------------
__global__ __launch_bounds__(256) void k6_mfma(const float* __restrict__ h,
    const u16* __restrict__ w1t, const u16* __restrict__ w2t,
    const float* __restrict__ b1, const float* __restrict__ b2,
    const float* __restrict__ wn2, float* __restrict__ out)
{
  __shared__ u16 tls[32 * 520];       // GELU tile, bf16, stride 520
  __shared__ float red[4][32];
  int tid = threadIdx.x;
  int w = tid >> 6, lane = tid & 63;
  int quad = lane >> 4, l16 = lane & 15;
  int row0 = blockIdx.x * 32;
  int ko = quad * 8;

  // ---- stage 1: t = GELU(h @ W1 + b1); wave w: cols 128w..128w+127
  f32x4v acc1[2][8];
#pragma unroll
  for (int mt = 0; mt < 2; ++mt)
#pragma unroll
    for (int nt = 0; nt < 8; ++nt) acc1[mt][nt] = (f32x4v){0.f, 0.f, 0.f, 0.f};
#pragma unroll
  for (int ks = 0; ks < 4; ++ks) {
    int k0 = ks * 32 + ko;
    s16x8 a[2];
#pragma unroll
    for (int mt = 0; mt < 2; ++mt) {
      int row = row0 + mt * 16 + l16; if (row >= NN) row = NN - 1;
      a[mt] = ld_bf16x8_f32(h + row * 128 + k0);
    }
#pragma unroll
    for (int nt = 0; nt < 8; ++nt) {
      int col = w * 128 + nt * 16 + l16;
      s16x8 b = *(const s16x8*)(w1t + col * 128 + k0);
      acc1[0][nt] = mfma16(a[0], b, acc1[0][nt]);
      acc1[1][nt] = mfma16(a[1], b, acc1[1][nt]);
    }
  }
#pragma unroll
  for (int nt = 0; nt < 8; ++nt) {
    int col = w * 128 + nt * 16 + l16;
    float bb = b1[col];
#pragma unroll
    for (int mt = 0; mt < 2; ++mt)
#pragma unroll
      for (int r = 0; r < 4; ++r) {
        float t = acc1[mt][nt][r] + bb;
        t = 0.5f * t * (1.f + erff(t * 0.70710678118654752f));   // exact GELU
        tls[(mt * 16 + quad * 4 + r) * 520 + col] = f2b(t);
      }
  }
  __syncthreads();

  // ---- stage 2: f = t @ W2 + b2; out = rmsnorm(h + f, wn2); wave w: cols 32w..32w+31
  f32x4v acc2[2][2];
#pragma unroll
  for (int mt = 0; mt < 2; ++mt)
#pragma unroll
    for (int nt = 0; nt < 2; ++nt) acc2[mt][nt] = (f32x4v){0.f, 0.f, 0.f, 0.f};
#pragma unroll
  for (int ks = 0; ks < 16; ++ks) {
    int k0 = ks * 32 + ko;
    s16x8 a2[2];
#pragma unroll
    for (int mt = 0; mt < 2; ++mt)
      a2[mt] = *(const s16x8*)(tls + (mt * 16 + l16) * 520 + k0);
#pragma unroll
    for (int nt = 0; nt < 2; ++nt) {
      int col = w * 32 + nt * 16 + l16;
      s16x8 b = *(const s16x8*)(w2t + col * 512 + k0);
      acc2[0][nt] = mfma16(a2[0], b, acc2[0][nt]);
      acc2[1][nt] = mfma16(a2[1], b, acc2[1][nt]);
    }
  }
  int cols[2]; float bb2[2], wn[2];
#pragma unroll
  for (int nt = 0; nt < 2; ++nt) {
    cols[nt] = w * 32 + nt * 16 + l16;
    bb2[nt] = b2[cols[nt]];
    wn[nt] = wn2[cols[nt]];
  }
  float ov[2][2][4];
#pragma unroll
  for (int mt = 0; mt < 2; ++mt)
#pragma unroll
    for (int r = 0; r < 4; ++r) {
      int row = row0 + mt * 16 + quad * 4 + r;
      int rowc = row < NN ? row : NN - 1;
#pragma unroll
      for (int nt = 0; nt < 2; ++nt)
        ov[mt][nt][r] = h[rowc * 128 + cols[nt]] + acc2[mt][nt][r] + bb2[nt];
    }
#pragma unroll
  for (int mt = 0; mt < 2; ++mt)
#pragma unroll
    for (int r = 0; r < 4; ++r) {
      float q = ov[mt][0][r] * ov[mt][0][r] + ov[mt][1][r] * ov[mt][1][r];
      q += __shfl_xor(q, 1); q += __shfl_xor(q, 2);
      q += __shfl_xor(q, 4); q += __shfl_xor(q, 8);
      if (l16 == 0) red[w][mt * 16 + quad * 4 + r] = q;
    }
  __syncthreads();
#pragma unroll
  for (int mt = 0; mt < 2; ++mt)
#pragma unroll
    for (int r = 0; r < 4; ++r) {
      int rl = mt * 16 + quad * 4 + r;
      float tot = red[0][rl] + red[1][rl] + red[2][rl] + red[3][rl];
      float rr = rsqrtf(tot * (1.f / 128.f) + RMS_EPS);
      int row = row0 + rl;
      if (row < NN) {
        out[row * 128 + cols[0]] = ov[mt][0][r] * rr * wn[0];
        out[row * 128 + cols[1]] = ov[mt][1][r] * rr * wn[1];
      }
    }
}

// ---------------- launch ----------------
extern "C" void kernel_launch(void* const* d_in, const int* in_sizes, int n_in,
                              void* d_out, int out_size, void* d_ws, size_t ws_size,
                              hipStream_t stream) {
  const float* x   = (const float*)d_in[0];
  const int*   ei  = (const int*)d_in[1];
  const float* ea  = (const float*)d_in[2];
  const float* Wl  = (const float*)d_in[3];
  const float* bl  = (const float*)d_in[4];
  const float* Wr  = (const float*)d_in[5];
  const float* br  = (const float*)d_in[6];
  const float* We  = (const float*)d_in[7];
  const float* att = (const float*)d_in[8];
  const float* bg  = (const float*)d_in[9];
  const float* wn1 = (const float*)d_in[10];
  const float* wn2 = (const float*)d_in[11];
  const float* W1  = (const float*)d_in[12];
  const float* b1  = (const float*)d_in[13];
  const float* W2  = (const float*)d_in[14];
  const float* b2  = (const float*)d_in[15];

  float* wsf = (float*)d_ws;
  int*   wsi = (int*)d_ws;

  float* xl   = wsf + OFF_XL;
  float* xr   = wsf + OFF_XR;
  float* gat  = wsf + OFF_XR;   // alias: xr dead after k2a
  float* hbuf = wsf + OFF_XL;   // alias: xl dead after k2c
  float* lgp  = wsf + OFF_LGP;
  u16* wlrt   = (u16*)(wsf + OFF_WLRT);
  u16* w1t    = (u16*)(wsf + OFF_W1T);
  u16* w2t    = (u16*)(wsf + OFF_W2T);
  int* cnt    = wsi + OFF_CNT;
  int* pos    = wsi + OFF_CNT;  // alias: scan rebuilds cnt as cursor array in-place
  int* offs   = wsi + OFF_OFS;
  int* srcarr = wsi + OFF_SRC;

  // prep
  k_zero<<<(NN + 255) / 256, 256, 0, stream>>>(cnt, NN);
  k_tcvt2<<<128, 256, 0, stream>>>(Wl, Wr, wlrt);
  k_t1<<<256, 256, 0, stream>>>(W1, w1t);
  k_t2<<<256, 256, 0, stream>>>(W2, w2t);

  // CSR structure (before k2a)
  k_hist<<<(EE + 255) / 256, 256, 0, stream>>>(ei, cnt);
  k_scan<<<1, 1024, 0, stream>>>(cnt, offs, pos);

  // node transforms (MFMA, in-register bf16 cvt)
  k1_mfma<<<(NN + 31) / 32, 256, 0, stream>>>(x, wlrt, bl, br, xl, xr);

  // per-edge logits + fused CSR scatter
  k2a_logits<<<1024, 256, 0, stream>>>(ei, ea, att, We, xl, xr, pos, srcarr, lgp);

  // softmax + weighted accumulation
  k2c_attn<<<1024, 256, 0, stream>>>(offs, srcarr, lgp, xl, gat);

  // norm1
  k5_norm1<<<NN / 4, 256, 0, stream>>>(x, gat, bg, wn1, hbuf);

  // fused FFN (MFMA) + residual + norm2
  k6_mfma<<<(NN + 31) / 32, 256, 0, stream>>>(hbuf, w1t, w2t, b1, b2, wn2, (float*)d_out);
}

// Round 7
// 586.943 us; speedup vs baseline: 1.7031x; 1.3065x over previous
//
#include <hip/hip_runtime.h>

// ---------------- problem constants ----------------
#define NN 50000
#define EE 800000
// HID=128, EDGE_DIM=16, HEADS=4, C=32

typedef unsigned short u16;

// ---------------- ws layout (4-byte element offsets), total ~58.3 MB ----------------
// Region A: gat (live k2..k5)
#define OFF_GAT  0u          // N*128 f32 = 6,400,000 slots
// Region B: k1/k2 operands; dead after k2 -> h aliases XLB+XRB exactly
#define OFF_XLB  6400000u    // N*128 bf16 = 3,200,000 f32 slots -> 6.4M..9.6M
#define OFF_XRB  9600000u    // N*128 bf16 = 3,200,000 f32 slots -> 9.6M..12.8M
#define OFF_SRC  12800000u   // E ints (CSR-ordered src)        -> 12.8M..13.6M
#define OFF_EID  13600000u   // E ints (CSR-ordered edge id)    -> 13.6M..14.4M
#define OFF_CNT  14400000u   // N ints (hist; then CSR cursors) -> 14.4M..14.45M
#define OFF_OFS  14450000u   // N+1 ints                        -> 14.45M..14,500,001
#define OFF_H    6400000u    // N*128 f32, aliases XLB+XRB (6.4M..12.8M), after k2
// Region C: weights (live to the end), 16B-aligned offsets
#define OFF_WLRT 14500004u   // 256x128 bf16 = 16,384 f32 slots
#define OFF_W1T  14516388u   // 512x128 bf16 = 32,768 f32 slots
#define OFF_W2T  14549156u   // 128x512 bf16 = 32,768 f32 slots
// end: 14,581,924 f32 = 58,327,696 bytes (< proven 67.9 MB budget)

#define RMS_EPS 1.1920928955078125e-7f

typedef float f32x4v __attribute__((ext_vector_type(4)));
typedef short s16x8 __attribute__((ext_vector_type(8)));

__device__ __forceinline__ f32x4v mfma16(s16x8 a, s16x8 b, f32x4v c) {
  return __builtin_amdgcn_mfma_f32_16x16x32_bf16(a, b, c, 0, 0, 0);
}
__device__ __forceinline__ u16 f2b(float f) {
  unsigned int u = __float_as_uint(f);
  unsigned int r = (u + 0x7fffu + ((u >> 16) & 1u)) >> 16;
  return (u16)r;
}
__device__ __forceinline__ float b2f(u16 u) {
  union { float f; unsigned int i; } x; x.i = ((unsigned int)u) << 16; return x.f;
}
// load 8 fp32, convert to bf16 fragment in-register
__device__ __forceinline__ s16x8 ld_bf16x8_f32(const float* __restrict__ p) {
  float4 v0 = *(const float4*)p;
  float4 v1 = *(const float4*)(p + 4);
  s16x8 r;
  r[0] = (short)f2b(v0.x); r[1] = (short)f2b(v0.y);
  r[2] = (short)f2b(v0.z); r[3] = (short)f2b(v0.w);
  r[4] = (short)f2b(v1.x); r[5] = (short)f2b(v1.y);
  r[6] = (short)f2b(v1.z); r[7] = (short)f2b(v1.w);
  return r;
}
__device__ __forceinline__ float readlane_f32(float v, int lane) {
  return __int_as_float(__builtin_amdgcn_readlane(__float_as_int(v), lane));
}
__device__ __forceinline__ int readlane_i32(int v, int lane) {
  return __builtin_amdgcn_readlane(v, lane);
}

// ---------------- utility kernels ----------------
__global__ __launch_bounds__(256) void k_zero(int* __restrict__ p, int n) {
  int i = blockIdx.x * 256 + threadIdx.x;
  if (i < n) p[i] = 0;
}
__global__ __launch_bounds__(256) void k_tcvt2(const float* __restrict__ Wl, const float* __restrict__ Wr,
                                               u16* __restrict__ out) {
  int i = blockIdx.x * 256 + threadIdx.x;  // 32768
  int n = i >> 7, k = i & 127;
  float v = (n < 128) ? Wl[k * 128 + n] : Wr[k * 128 + (n - 128)];
  out[i] = f2b(v);
}
__global__ __launch_bounds__(256) void k_t1(const float* __restrict__ W1, u16* __restrict__ out) {
  int i = blockIdx.x * 256 + threadIdx.x;  // 65536
  int n = i >> 7, k = i & 127;
  out[i] = f2b(W1[k * 512 + n]);
}
__global__ __launch_bounds__(256) void k_t2(const float* __restrict__ W2, u16* __restrict__ out) {
  int i = blockIdx.x * 256 + threadIdx.x;  // 65536
  int n = i >> 9, k = i & 511;
  out[i] = f2b(W2[k * 128 + n]);
}

// ---------------- CSR build ----------------
__global__ __launch_bounds__(256) void k_hist(const int* __restrict__ ei, int* __restrict__ cnt) {
  int e = blockIdx.x * 256 + threadIdx.x;
  if (e < EE) atomicAdd(&cnt[ei[EE + e]], 1);
}

// scan: offs = exclusive prefix (N+1); pos (aliases cnt, in-place) = cursors
__global__ __launch_bounds__(1024) void k_scan(const int* __restrict__ cnt,
    int* __restrict__ offs, int* __restrict__ pos)
{
  __shared__ int wsum[16];
  __shared__ int carry_s;
  int tid = threadIdx.x, lane = tid & 63, wv = tid >> 6;
  if (tid == 0) carry_s = 0;
  __syncthreads();
  for (int base = 0; base < NN; base += 1024) {
    int i = base + tid;
    int v = (i < NN) ? cnt[i] : 0;
    int x = v;
#pragma unroll
    for (int ofs = 1; ofs < 64; ofs <<= 1) {
      int y = __shfl_up(x, ofs);
      if (lane >= ofs) x += y;
    }
    if (lane == 63) wsum[wv] = x;
    __syncthreads();
    if (wv == 0) {
      int s = (lane < 16) ? wsum[lane] : 0;
#pragma unroll
      for (int ofs = 1; ofs < 16; ofs <<= 1) {
        int y = __shfl_up(s, ofs);
        if (lane >= ofs) s += y;
      }
      if (lane < 16) wsum[lane] = s;
    }
    __syncthreads();
    int wbase = (wv > 0) ? wsum[wv - 1] : 0;
    int incl = x + wbase + carry_s;
    if (i < NN) { offs[i + 1] = incl; pos[i] = incl - v; }
    if (base == 0 && tid == 0) offs[0] = 0;
    __syncthreads();
    if (tid == 1023) carry_s = incl;
    __syncthreads();
  }
}

// permute: CSR-ordered (src, edge-id)
__global__ __launch_bounds__(256) void k_permute(const int* __restrict__ ei,
    int* __restrict__ pos, int* __restrict__ srcarr, int* __restrict__ eidarr)
{
  int e = blockIdx.x * 256 + threadIdx.x;
  if (e < EE) {
    int slot = atomicAdd(&pos[ei[EE + e]], 1);
    srcarr[slot] = ei[e];
    eidarr[slot] = e;
  }
}

// ---------------- K1: [xl|xr] = x @ [Wl|Wr] + [bl|br] -> bf16 ----------------
__global__ __launch_bounds__(256) void k1_mfma(const float* __restrict__ x, const u16* __restrict__ wlrt,
    const float* __restrict__ bl, const float* __restrict__ br,
    u16* __restrict__ xlb, u16* __restrict__ xrb)
{
  int tid = threadIdx.x;
  int w = tid >> 6, lane = tid & 63;
  int quad = lane >> 4, l16 = lane & 15;
  int row0 = blockIdx.x * 32;
  int ko = quad * 8;
  f32x4v acc[2][4];
#pragma unroll
  for (int mt = 0; mt < 2; ++mt)
#pragma unroll
    for (int nt = 0; nt < 4; ++nt) acc[mt][nt] = (f32x4v){0.f, 0.f, 0.f, 0.f};
#pragma unroll
  for (int ks = 0; ks < 4; ++ks) {
    int k0 = ks * 32 + ko;
    s16x8 a[2];
#pragma unroll
    for (int mt = 0; mt < 2; ++mt) {
      int row = row0 + mt * 16 + l16; if (row >= NN) row = NN - 1;
      a[mt] = ld_bf16x8_f32(x + row * 128 + k0);
    }
#pragma unroll
    for (int nt = 0; nt < 4; ++nt) {
      int col = w * 64 + nt * 16 + l16;
      s16x8 b = *(const s16x8*)(wlrt + col * 128 + k0);
      acc[0][nt] = mfma16(a[0], b, acc[0][nt]);
      acc[1][nt] = mfma16(a[1], b, acc[1][nt]);
    }
  }
#pragma unroll
  for (int nt = 0; nt < 4; ++nt) {
    int col = w * 64 + nt * 16 + l16;
    bool isl = col < 128;
    float bias = isl ? bl[col] : br[col - 128];
    u16* dst = isl ? xlb : xrb;
    int cc = isl ? col : col - 128;
#pragma unroll
    for (int mt = 0; mt < 2; ++mt)
#pragma unroll
      for (int r = 0; r < 4; ++r) {
        int row = row0 + mt * 16 + quad * 4 + r;
        if (row < NN) dst[row * 128 + cc] = f2b(acc[mt][nt][r] + bias);
      }
  }
}

// ---------------- K2: fused logits + online softmax + weighted accum (wave/dst) ----------------
__global__ __launch_bounds__(256) void k2_attn(
    const int* __restrict__ offs, const int* __restrict__ srcarr,
    const int* __restrict__ eidarr, const float* __restrict__ eattr,
    const float* __restrict__ att, const float* __restrict__ We,
    const u16* __restrict__ xlb, const u16* __restrict__ xrb,
    float* __restrict__ gat)
{
  int l = threadIdx.x & 63;
  int wid = (blockIdx.x * blockDim.x + threadIdx.x) >> 6;
  int nw = (gridDim.x * blockDim.x) >> 6;
  int c0 = 2 * l;
  const float2* We2 = (const float2*)We;   // [16][64] float2: cols 2l,2l+1
  float2 wef[16];
#pragma unroll
  for (int k = 0; k < 16; ++k) wef[k] = We2[k * 64 + l];
  float a0 = att[c0], a1 = att[c0 + 1];
  for (int d = wid; d < NN; d += nw) {
    int start = offs[d];
    int deg = offs[d + 1] - start;
    // xr[dst] loaded once
    ushort2 xru = *(const ushort2*)(xrb + d * 128 + c0);
    float xr0 = b2f(xru.x), xr1 = b2f(xru.y);
    // online-softmax state (mh, lh replicated within 16-lane head group)
    float mh = -1e30f, lh = 0.f, O0 = 0.f, O1 = 0.f;
    for (int base = 0; base < deg; base += 64) {
      bool act = (base + l) < deg;
      int idx = start + base + l;
      int sv = act ? srcarr[idx] : 0;
      int ev = act ? eidarr[idx] : 0;
      int cnt = min(64, deg - base);
      for (int sub = 0; sub < cnt; sub += 4) {
        // eattr rows for 4 edges: lane l covers edge (l>>4), dim (l&15)
        int eidq = __shfl(ev, sub + (l >> 4));
        float eav = eattr[eidq * 16 + (l & 15)];
#pragma unroll
        for (int j2 = 0; j2 < 4; ++j2) {
          int j = sub + j2;
          if (j >= cnt) break;
          int sr = readlane_i32(sv, j);
          // e-projection for dims c0,c0+1
          float ep0 = 0.f, ep1 = 0.f;
#pragma unroll
          for (int k = 0; k < 16; ++k) {
            float ek = readlane_f32(eav, j2 * 16 + k);
            ep0 = fmaf(ek, wef[k].x, ep0);
            ep1 = fmaf(ek, wef[k].y, ep1);
          }
          ushort2 xlu = *(const ushort2*)(xlb + sr * 128 + c0);
          float xl0 = b2f(xlu.x), xl1 = b2f(xlu.y);
          float m0 = xl0 + xr0 + ep0;
          float m1 = xl1 + xr1 + ep1;
          float s0 = m0 > 0.f ? m0 : 0.2f * m0;   // LeakyReLU(0.2)
          float s1 = m1 > 0.f ? m1 : 0.2f * m1;
          float p = fmaf(s0, a0, s1 * a1);
          // reduce logit within 16-lane head group
          p += __shfl_xor(p, 1); p += __shfl_xor(p, 2);
          p += __shfl_xor(p, 4); p += __shfl_xor(p, 8);
          // online update
          float nm = fmaxf(mh, p);
          float sc = __expf(mh - nm);
          float wgt = __expf(p - nm);
          lh = lh * sc + wgt;
          O0 = fmaf(wgt, xl0, O0 * sc);
          O1 = fmaf(wgt, xl1, O1 * sc);
          mh = nm;
        }
      }
    }
    float inv = 1.f / (lh + 1e-16f);
    *(float2*)(gat + d * 128 + c0) = make_float2(O0 * inv, O1 * inv);
  }
}

// ---------------- K5: h = rmsnorm(x + gat + bias_gat, w_norm1) ----------------
__global__ __launch_bounds__(256) void k5_norm1(const float* __restrict__ x,
    const float* __restrict__ gat, const float* __restrict__ bg,
    const float* __restrict__ wn1, float* __restrict__ h)
{
  int l = threadIdx.x & 63;
  int row = blockIdx.x * 4 + (threadIdx.x >> 6);
  int c0 = 2 * l;
  float2 xu = *(const float2*)(x + row * 128 + c0);
  float2 gv = *(const float2*)(gat + row * 128 + c0);
  float2 bu = *(const float2*)(bg + c0);
  float v0 = xu.x + gv.x + bu.x;
  float v1 = xu.y + gv.y + bu.y;
  float ss = v0 * v0 + v1 * v1;
#pragma unroll
  for (int o = 1; o < 64; o <<= 1) ss += __shfl_xor(ss, o);
  float rr = rsqrtf(ss * (1.f / 128.f) + RMS_EPS);
  float2 wu = *(const float2*)(wn1 + c0);
  *(float2*)(h + row * 128 + c0) = make_float2(v0 * rr * wu.x, v1 * rr * wu.y);
}

// ---------------- K6: fused FFN (bf16 MFMA, fp32 src) + residual + rmsnorm2 ----------------
__global__ __launch_bounds__(256) void k6_mfma(const float* __restrict__ h,
    const u16* __restrict__ w1t, const u16* __restrict__ w2t,
    const float* __restrict__ b1, const float* __restrict__ b2,
    const float* __restrict__ wn2, float* __restrict__ out)
{
  __shared__ u16 tls[32 * 520];
  __shared__ float red[4][32];
  int tid = threadIdx.x;
  int w = tid >> 6, lane = tid & 63;
  int quad = lane >> 4, l16 = lane & 15;
  int row0 = blockIdx.x * 32;
  int ko = quad * 8;

  f32x4v acc1[2][8];
#pragma unroll
  for (int mt = 0; mt < 2; ++mt)
#pragma unroll
    for (int nt = 0; nt < 8; ++nt) acc1[mt][nt] = (f32x4v){0.f, 0.f, 0.f, 0.f};
#pragma unroll
  for (int ks = 0; ks < 4; ++ks) {
    int k0 = ks * 32 + ko;
    s16x8 a[2];
#pragma unroll
    for (int mt = 0; mt < 2; ++mt) {
      int row = row0 + mt * 16 + l16; if (row >= NN) row = NN - 1;
      a[mt] = ld_bf16x8_f32(h + row * 128 + k0);
    }
#pragma unroll
    for (int nt = 0; nt < 8; ++nt) {
      int col = w * 128 + nt * 16 + l16;
      s16x8 b = *(const s16x8*)(w1t + col * 128 + k0);
      acc1[0][nt] = mfma16(a[0], b, acc1[0][nt]);
      acc1[1][nt] = mfma16(a[1], b, acc1[1][nt]);
    }
  }
#pragma unroll
  for (int nt = 0; nt < 8; ++nt) {
    int col = w * 128 + nt * 16 + l16;
    float bb = b1[col];
#pragma unroll
    for (int mt = 0; mt < 2; ++mt)
#pragma unroll
      for (int r = 0; r < 4; ++r) {
        float t = acc1[mt][nt][r] + bb;
        t = 0.5f * t * (1.f + erff(t * 0.70710678118654752f));
        tls[(mt * 16 + quad * 4 + r) * 520 + col] = f2b(t);
      }
  }
  __syncthreads();

  f32x4v acc2[2][2];
#pragma unroll
  for (int mt = 0; mt < 2; ++mt)
#pragma unroll
    for (int nt = 0; nt < 2; ++nt) acc2[mt][nt] = (f32x4v){0.f, 0.f, 0.f, 0.f};
#pragma unroll
  for (int ks = 0; ks < 16; ++ks) {
    int k0 = ks * 32 + ko;
    s16x8 a2[2];
#pragma unroll
    for (int mt = 0; mt < 2; ++mt)
      a2[mt] = *(const s16x8*)(tls + (mt * 16 + l16) * 520 + k0);
#pragma unroll
    for (int nt = 0; nt < 2; ++nt) {
      int col = w * 32 + nt * 16 + l16;
      s16x8 b = *(const s16x8*)(w2t + col * 512 + k0);
      acc2[0][nt] = mfma16(a2[0], b, acc2[0][nt]);
      acc2[1][nt] = mfma16(a2[1], b, acc2[1][nt]);
    }
  }
  int cols[2]; float bb2[2], wn[2];
#pragma unroll
  for (int nt = 0; nt < 2; ++nt) {
    cols[nt] = w * 32 + nt * 16 + l16;
    bb2[nt] = b2[cols[nt]];
    wn[nt] = wn2[cols[nt]];
  }
  float ov[2][2][4];
#pragma unroll
  for (int mt = 0; mt < 2; ++mt)
#pragma unroll
    for (int r = 0; r < 4; ++r) {
      int row = row0 + mt * 16 + quad * 4 + r;
      int rowc = row < NN ? row : NN - 1;
#pragma unroll
      for (int nt = 0; nt < 2; ++nt)
        ov[mt][nt][r] = h[rowc * 128 + cols[nt]] + acc2[mt][nt][r] + bb2[nt];
    }
#pragma unroll
  for (int mt = 0; mt < 2; ++mt)
#pragma unroll
    for (int r = 0; r < 4; ++r) {
      float q = ov[mt][0][r] * ov[mt][0][r] + ov[mt][1][r] * ov[mt][1][r];
      q += __shfl_xor(q, 1); q += __shfl_xor(q, 2);
      q += __shfl_xor(q, 4); q += __shfl_xor(q, 8);
      if (l16 == 0) red[w][mt * 16 + quad * 4 + r] = q;
    }
  __syncthreads();
#pragma unroll
  for (int mt = 0; mt < 2; ++mt)
#pragma unroll
    for (int r = 0; r < 4; ++r) {
      int rl = mt * 16 + quad * 4 + r;
      float tot = red[0][rl] + red[1][rl] + red[2][rl] + red[3][rl];
      float rr = rsqrtf(tot * (1.f / 128.f) + RMS_EPS);
      int row = row0 + rl;
      if (row < NN) {
        out[row * 128 + cols[0]] = ov[mt][0][r] * rr * wn[0];
        out[row * 128 + cols[1]] = ov[mt][1][r] * rr * wn[1];
      }
    }
}

// ---------------- launch ----------------
extern "C" void kernel_launch(void* const* d_in, const int* in_sizes, int n_in,
                              void* d_out, int out_size, void* d_ws, size_t ws_size,
                              hipStream_t stream) {
  const float* x   = (const float*)d_in[0];
  const int*   ei  = (const int*)d_in[1];
  const float* ea  = (const float*)d_in[2];
  const float* Wl  = (const float*)d_in[3];
  const float* bl  = (const float*)d_in[4];
  const float* Wr  = (const float*)d_in[5];
  const float* br  = (const float*)d_in[6];
  const float* We  = (const float*)d_in[7];
  const float* att = (const float*)d_in[8];
  const float* bg  = (const float*)d_in[9];
  const float* wn1 = (const float*)d_in[10];
  const float* wn2 = (const float*)d_in[11];
  const float* W1  = (const float*)d_in[12];
  const float* b1  = (const float*)d_in[13];
  const float* W2  = (const float*)d_in[14];
  const float* b2  = (const float*)d_in[15];

  float* wsf = (float*)d_ws;
  int*   wsi = (int*)d_ws;

  float* gat  = wsf + OFF_GAT;
  u16* xlb    = (u16*)(wsf + OFF_XLB);
  u16* xrb    = (u16*)(wsf + OFF_XRB);
  int* srcarr = wsi + OFF_SRC;
  int* eidarr = wsi + OFF_EID;
  int* cnt    = wsi + OFF_CNT;
  int* pos    = wsi + OFF_CNT;   // alias: scan rebuilds in-place as cursors
  int* offs   = wsi + OFF_OFS;
  float* hbuf = wsf + OFF_H;     // aliases xlb+xrb (dead after k2)
  u16* wlrt   = (u16*)(wsf + OFF_WLRT);
  u16* w1t    = (u16*)(wsf + OFF_W1T);
  u16* w2t    = (u16*)(wsf + OFF_W2T);

  // prep
  k_zero<<<(NN + 255) / 256, 256, 0, stream>>>(cnt, NN);
  k_tcvt2<<<128, 256, 0, stream>>>(Wl, Wr, wlrt);
  k_t1<<<256, 256, 0, stream>>>(W1, w1t);
  k_t2<<<256, 256, 0, stream>>>(W2, w2t);

  // CSR structure
  k_hist<<<(EE + 255) / 256, 256, 0, stream>>>(ei, cnt);
  k_scan<<<1, 1024, 0, stream>>>(cnt, offs, pos);
  k_permute<<<(EE + 255) / 256, 256, 0, stream>>>(ei, pos, srcarr, eidarr);

  // node transforms (MFMA) -> bf16
  k1_mfma<<<(NN + 31) / 32, 256, 0, stream>>>(x, wlrt, bl, br, xlb, xrb);

  // fused logits + online softmax + weighted accumulation
  k2_attn<<<1024, 256, 0, stream>>>(offs, srcarr, eidarr, ea, att, We, xlb, xrb, gat);

  // norm1
  k5_norm1<<<NN / 4, 256, 0, stream>>>(x, gat, bg, wn1, hbuf);

  // fused FFN (MFMA) + residual + norm2
  k6_mfma<<<(NN + 31) / 32, 256, 0, stream>>>(hbuf, w1t, w2t, b1, b2, wn2, (float*)d_out);
}

// Round 8
// 550.458 us; speedup vs baseline: 1.8160x; 1.0663x over previous
//
#include <hip/hip_runtime.h>

// ---------------- problem constants ----------------
#define NN 50000
#define EE 800000
// HID=128, EDGE_DIM=16, HEADS=4, C=32

typedef unsigned short u16;

// ---------------- ws layout (4-byte element offsets), total ~58.3 MB ----------------
// Region A: gat (live k2..k5)
#define OFF_GAT  0u          // N*128 f32 = 6,400,000 slots
// Region B: k1/k2 operands; dead after k2 -> h aliases XLB+XRB exactly
#define OFF_XLB  6400000u    // N*128 bf16 = 3,200,000 f32 slots -> 6.4M..9.6M
#define OFF_XRB  9600000u    // N*128 bf16 = 3,200,000 f32 slots -> 9.6M..12.8M
#define OFF_SE   12800000u   // E int2 (CSR-ordered {src, eid})  -> 12.8M..14.4M
#define OFF_CNT  14400000u   // N ints (hist; then CSR cursors)  -> 14.4M..14.45M
#define OFF_OFS  14450000u   // N+1 ints
#define OFF_H    6400000u    // N*128 f32, aliases XLB+XRB (6.4M..12.8M), after k2
// Region C: weights (live to the end), 16B-aligned offsets
#define OFF_WLRT 14500004u   // 256x128 bf16 = 16,384 f32 slots
#define OFF_W1T  14516388u   // 512x128 bf16 = 32,768 f32 slots
#define OFF_W2T  14549156u   // 128x512 bf16 = 32,768 f32 slots
// end: 14,581,924 f32 = 58,327,696 bytes (< proven 67.9 MB budget)

#define RMS_EPS 1.1920928955078125e-7f

typedef float f32x4v __attribute__((ext_vector_type(4)));
typedef short s16x8 __attribute__((ext_vector_type(8)));

__device__ __forceinline__ f32x4v mfma16(s16x8 a, s16x8 b, f32x4v c) {
  return __builtin_amdgcn_mfma_f32_16x16x32_bf16(a, b, c, 0, 0, 0);
}
__device__ __forceinline__ u16 f2b(float f) {
  unsigned int u = __float_as_uint(f);
  unsigned int r = (u + 0x7fffu + ((u >> 16) & 1u)) >> 16;
  return (u16)r;
}
__device__ __forceinline__ float b2f(u16 u) {
  union { float f; unsigned int i; } x; x.i = ((unsigned int)u) << 16; return x.f;
}
// load 8 fp32, convert to bf16 fragment in-register
__device__ __forceinline__ s16x8 ld_bf16x8_f32(const float* __restrict__ p) {
  float4 v0 = *(const float4*)p;
  float4 v1 = *(const float4*)(p + 4);
  s16x8 r;
  r[0] = (short)f2b(v0.x); r[1] = (short)f2b(v0.y);
  r[2] = (short)f2b(v0.z); r[3] = (short)f2b(v0.w);
  r[4] = (short)f2b(v1.x); r[5] = (short)f2b(v1.y);
  r[6] = (short)f2b(v1.z); r[7] = (short)f2b(v1.w);
  return r;
}
__device__ __forceinline__ float readlane_f32(float v, int lane) {
  return __int_as_float(__builtin_amdgcn_readlane(__float_as_int(v), lane));
}
__device__ __forceinline__ int readlane_i32(int v, int lane) {
  return __builtin_amdgcn_readlane(v, lane);
}

// ---------------- fused prep: zero hist + 3 weight transposes (bf16) ----------------
__global__ __launch_bounds__(256) void k_prep(const float* __restrict__ Wl, const float* __restrict__ Wr,
    const float* __restrict__ W1, const float* __restrict__ W2,
    int* __restrict__ cnt, u16* __restrict__ wlrt, u16* __restrict__ w1t, u16* __restrict__ w2t)
{
  int i = blockIdx.x * 256 + threadIdx.x;   // 65536 threads
  if (i < NN) cnt[i] = 0;
  if (i < 32768) {
    int n = i >> 7, k = i & 127;
    float v = (n < 128) ? Wl[k * 128 + n] : Wr[k * 128 + (n - 128)];
    wlrt[i] = f2b(v);
  }
  {
    int n = i >> 7, k = i & 127;
    w1t[i] = f2b(W1[k * 512 + n]);
  }
  {
    int n = i >> 9, k = i & 511;
    w2t[i] = f2b(W2[k * 128 + n]);
  }
}

// ---------------- CSR build ----------------
__global__ __launch_bounds__(256) void k_hist(const int* __restrict__ ei, int* __restrict__ cnt) {
  int e = blockIdx.x * 256 + threadIdx.x;
  if (e < EE) atomicAdd(&cnt[ei[EE + e]], 1);
}

// scan: offs = exclusive prefix (N+1); pos (aliases cnt, in-place) = cursors
__global__ __launch_bounds__(1024) void k_scan(const int* __restrict__ cnt,
    int* __restrict__ offs, int* __restrict__ pos)
{
  __shared__ int wsum[16];
  __shared__ int carry_s;
  int tid = threadIdx.x, lane = tid & 63, wv = tid >> 6;
  if (tid == 0) carry_s = 0;
  __syncthreads();
  for (int base = 0; base < NN; base += 1024) {
    int i = base + tid;
    int v = (i < NN) ? cnt[i] : 0;
    int x = v;
#pragma unroll
    for (int ofs = 1; ofs < 64; ofs <<= 1) {
      int y = __shfl_up(x, ofs);
      if (lane >= ofs) x += y;
    }
    if (lane == 63) wsum[wv] = x;
    __syncthreads();
    if (wv == 0) {
      int s = (lane < 16) ? wsum[lane] : 0;
#pragma unroll
      for (int ofs = 1; ofs < 16; ofs <<= 1) {
        int y = __shfl_up(s, ofs);
        if (lane >= ofs) s += y;
      }
      if (lane < 16) wsum[lane] = s;
    }
    __syncthreads();
    int wbase = (wv > 0) ? wsum[wv - 1] : 0;
    int incl = x + wbase + carry_s;
    if (i < NN) { offs[i + 1] = incl; pos[i] = incl - v; }
    if (base == 0 && tid == 0) offs[0] = 0;
    __syncthreads();
    if (tid == 1023) carry_s = incl;
    __syncthreads();
  }
}

// permute: CSR-ordered {src, eid} packed, one 8B store per edge
__global__ __launch_bounds__(256) void k_permute(const int* __restrict__ ei,
    int* __restrict__ pos, int2* __restrict__ se)
{
  int e = blockIdx.x * 256 + threadIdx.x;
  if (e < EE) {
    int slot = atomicAdd(&pos[ei[EE + e]], 1);
    se[slot] = make_int2(ei[e], e);
  }
}

// ---------------- K1: [xl|xr] = x @ [Wl|Wr] + [bl|br] -> bf16 ----------------
__global__ __launch_bounds__(256) void k1_mfma(const float* __restrict__ x, const u16* __restrict__ wlrt,
    const float* __restrict__ bl, const float* __restrict__ br,
    u16* __restrict__ xlb, u16* __restrict__ xrb)
{
  int tid = threadIdx.x;
  int w = tid >> 6, lane = tid & 63;
  int quad = lane >> 4, l16 = lane & 15;
  int row0 = blockIdx.x * 32;
  int ko = quad * 8;
  f32x4v acc[2][4];
#pragma unroll
  for (int mt = 0; mt < 2; ++mt)
#pragma unroll
    for (int nt = 0; nt < 4; ++nt) acc[mt][nt] = (f32x4v){0.f, 0.f, 0.f, 0.f};
#pragma unroll
  for (int ks = 0; ks < 4; ++ks) {
    int k0 = ks * 32 + ko;
    s16x8 a[2];
#pragma unroll
    for (int mt = 0; mt < 2; ++mt) {
      int row = row0 + mt * 16 + l16; if (row >= NN) row = NN - 1;
      a[mt] = ld_bf16x8_f32(x + row * 128 + k0);
    }
#pragma unroll
    for (int nt = 0; nt < 4; ++nt) {
      int col = w * 64 + nt * 16 + l16;
      s16x8 b = *(const s16x8*)(wlrt + col * 128 + k0);
      acc[0][nt] = mfma16(a[0], b, acc[0][nt]);
      acc[1][nt] = mfma16(a[1], b, acc[1][nt]);
    }
  }
#pragma unroll
  for (int nt = 0; nt < 4; ++nt) {
    int col = w * 64 + nt * 16 + l16;
    bool isl = col < 128;
    float bias = isl ? bl[col] : br[col - 128];
    u16* dst = isl ? xlb : xrb;
    int cc = isl ? col : col - 128;
#pragma unroll
    for (int mt = 0; mt < 2; ++mt)
#pragma unroll
      for (int r = 0; r < 4; ++r) {
        int row = row0 + mt * 16 + quad * 4 + r;
        if (row < NN) dst[row * 128 + cc] = f2b(acc[mt][nt][r] + bias);
      }
  }
}

// ---------------- K2: fused logits + 4-edge-batched online softmax (wave/dst) ----------------
__global__ __launch_bounds__(256) void k2_attn(
    const int* __restrict__ offs, const int2* __restrict__ se,
    const float* __restrict__ eattr,
    const float* __restrict__ att, const float* __restrict__ We,
    const u16* __restrict__ xlb, const u16* __restrict__ xrb,
    float* __restrict__ gat)
{
  int l = threadIdx.x & 63;
  int wid = (blockIdx.x * blockDim.x + threadIdx.x) >> 6;
  int nw = (gridDim.x * blockDim.x) >> 6;
  int c0 = 2 * l;
  const float2* We2 = (const float2*)We;   // [16][64] float2: cols 2l,2l+1
  float2 wef[16];
#pragma unroll
  for (int k = 0; k < 16; ++k) wef[k] = We2[k * 64 + l];
  float a0 = att[c0], a1 = att[c0 + 1];
  for (int d = wid; d < NN; d += nw) {
    int start = offs[d];
    int deg = offs[d + 1] - start;
    ushort2 xru = *(const ushort2*)(xrb + d * 128 + c0);
    float xr0 = b2f(xru.x), xr1 = b2f(xru.y);
    float mh = -1e30f, lh = 0.f, O0 = 0.f, O1 = 0.f;
    for (int base = 0; base < deg; base += 64) {
      bool act = (base + l) < deg;
      int idx = start + base + l;
      int2 sev = act ? se[idx] : make_int2(0, 0);
      int cnt = min(64, deg - base);
      for (int sub = 0; sub < cnt; sub += 4) {
        // eattr rows for 4 edges: lane covers edge (l>>4), dim (l&15)
        int eidq = __shfl(sev.y, sub + (l >> 4));
        float eav = eattr[eidq * 16 + (l & 15)];
        float p[4], xl0v[4], xl1v[4];
#pragma unroll
        for (int j2 = 0; j2 < 4; ++j2) {
          float ep0 = 0.f, ep1 = 0.f;
#pragma unroll
          for (int k = 0; k < 16; ++k) {
            float ek = readlane_f32(eav, j2 * 16 + k);
            ep0 = fmaf(ek, wef[k].x, ep0);
            ep1 = fmaf(ek, wef[k].y, ep1);
          }
          int sr = readlane_i32(sev.x, sub + j2);   // inactive lanes hold 0 -> safe row
          ushort2 xlu = *(const ushort2*)(xlb + sr * 128 + c0);
          float xl0 = b2f(xlu.x), xl1 = b2f(xlu.y);
          float m0 = xl0 + xr0 + ep0;
          float m1 = xl1 + xr1 + ep1;
          float s0 = m0 > 0.f ? m0 : 0.2f * m0;   // LeakyReLU(0.2)
          float s1 = m1 > 0.f ? m1 : 0.2f * m1;
          p[j2] = fmaf(s0, a0, s1 * a1);
          xl0v[j2] = xl0; xl1v[j2] = xl1;
        }
        // 4 interleaved reduction trees over 16-lane head groups (ILP)
#pragma unroll
        for (int o = 1; o <= 8; o <<= 1) {
          p[0] += __shfl_xor(p[0], o);
          p[1] += __shfl_xor(p[1], o);
          p[2] += __shfl_xor(p[2], o);
          p[3] += __shfl_xor(p[3], o);
        }
        // mask tail edges AFTER reduction (exp -> 0, garbage*0 = 0, no NaN)
#pragma unroll
        for (int j2 = 0; j2 < 4; ++j2) if (sub + j2 >= cnt) p[j2] = -1e30f;
        // single batched online update for 4 edges
        float nm = fmaxf(fmaxf(fmaxf(p[0], p[1]), fmaxf(p[2], p[3])), mh);
        float sc = __expf(mh - nm);
        float w0 = __expf(p[0] - nm), w1 = __expf(p[1] - nm);
        float w2 = __expf(p[2] - nm), w3 = __expf(p[3] - nm);
        lh = fmaf(lh, sc, (w0 + w1) + (w2 + w3));
        O0 = fmaf(O0, sc, fmaf(w0, xl0v[0], fmaf(w1, xl0v[1], fmaf(w2, xl0v[2], w3 * xl0v[3]))));
        O1 = fmaf(O1, sc, fmaf(w0, xl1v[0], fmaf(w1, xl1v[1], fmaf(w2, xl1v[2], w3 * xl1v[3]))));
        mh = nm;
      }
    }
    float inv = 1.f / (lh + 1e-16f);
    *(float2*)(gat + d * 128 + c0) = make_float2(O0 * inv, O1 * inv);
  }
}

// ---------------- K5: h = rmsnorm(x + gat + bias_gat, w_norm1) ----------------
__global__ __launch_bounds__(256) void k5_norm1(const float* __restrict__ x,
    const float* __restrict__ gat, const float* __restrict__ bg,
    const float* __restrict__ wn1, float* __restrict__ h)
{
  int l = threadIdx.x & 63;
  int row = blockIdx.x * 4 + (threadIdx.x >> 6);
  int c0 = 2 * l;
  float2 xu = *(const float2*)(x + row * 128 + c0);
  float2 gv = *(const float2*)(gat + row * 128 + c0);
  float2 bu = *(const float2*)(bg + c0);
  float v0 = xu.x + gv.x + bu.x;
  float v1 = xu.y + gv.y + bu.y;
  float ss = v0 * v0 + v1 * v1;
#pragma unroll
  for (int o = 1; o < 64; o <<= 1) ss += __shfl_xor(ss, o);
  float rr = rsqrtf(ss * (1.f / 128.f) + RMS_EPS);
  float2 wu = *(const float2*)(wn1 + c0);
  *(float2*)(h + row * 128 + c0) = make_float2(v0 * rr * wu.x, v1 * rr * wu.y);
}

// ---------------- K6: fused FFN (bf16 MFMA, fp32 src) + residual + rmsnorm2 ----------------
__global__ __launch_bounds__(256) void k6_mfma(const float* __restrict__ h,
    const u16* __restrict__ w1t, const u16* __restrict__ w2t,
    const float* __restrict__ b1, const float* __restrict__ b2,
    const float* __restrict__ wn2, float* __restrict__ out)
{
  __shared__ u16 tls[32 * 520];
  __shared__ float red[4][32];
  int tid = threadIdx.x;
  int w = tid >> 6, lane = tid & 63;
  int quad = lane >> 4, l16 = lane & 15;
  int row0 = blockIdx.x * 32;
  int ko = quad * 8;

  f32x4v acc1[2][8];
#pragma unroll
  for (int mt = 0; mt < 2; ++mt)
#pragma unroll
    for (int nt = 0; nt < 8; ++nt) acc1[mt][nt] = (f32x4v){0.f, 0.f, 0.f, 0.f};
#pragma unroll
  for (int ks = 0; ks < 4; ++ks) {
    int k0 = ks * 32 + ko;
    s16x8 a[2];
#pragma unroll
    for (int mt = 0; mt < 2; ++mt) {
      int row = row0 + mt * 16 + l16; if (row >= NN) row = NN - 1;
      a[mt] = ld_bf16x8_f32(h + row * 128 + k0);
    }
#pragma unroll
    for (int nt = 0; nt < 8; ++nt) {
      int col = w * 128 + nt * 16 + l16;
      s16x8 b = *(const s16x8*)(w1t + col * 128 + k0);
      acc1[0][nt] = mfma16(a[0], b, acc1[0][nt]);
      acc1[1][nt] = mfma16(a[1], b, acc1[1][nt]);
    }
  }
#pragma unroll
  for (int nt = 0; nt < 8; ++nt) {
    int col = w * 128 + nt * 16 + l16;
    float bb = b1[col];
#pragma unroll
    for (int mt = 0; mt < 2; ++mt)
#pragma unroll
      for (int r = 0; r < 4; ++r) {
        float t = acc1[mt][nt][r] + bb;
        t = 0.5f * t * (1.f + erff(t * 0.70710678118654752f));
        tls[(mt * 16 + quad * 4 + r) * 520 + col] = f2b(t);
      }
  }
  __syncthreads();

  f32x4v acc2[2][2];
#pragma unroll
  for (int mt = 0; mt < 2; ++mt)
#pragma unroll
    for (int nt = 0; nt < 2; ++nt) acc2[mt][nt] = (f32x4v){0.f, 0.f, 0.f, 0.f};
#pragma unroll
  for (int ks = 0; ks < 16; ++ks) {
    int k0 = ks * 32 + ko;
    s16x8 a2[2];
#pragma unroll
    for (int mt = 0; mt < 2; ++mt)
      a2[mt] = *(const s16x8*)(tls + (mt * 16 + l16) * 520 + k0);
#pragma unroll
    for (int nt = 0; nt < 2; ++nt) {
      int col = w * 32 + nt * 16 + l16;
      s16x8 b = *(const s16x8*)(w2t + col * 512 + k0);
      acc2[0][nt] = mfma16(a2[0], b, acc2[0][nt]);
      acc2[1][nt] = mfma16(a2[1], b, acc2[1][nt]);
    }
  }
  int cols[2]; float bb2[2], wn[2];
#pragma unroll
  for (int nt = 0; nt < 2; ++nt) {
    cols[nt] = w * 32 + nt * 16 + l16;
    bb2[nt] = b2[cols[nt]];
    wn[nt] = wn2[cols[nt]];
  }
  float ov[2][2][4];
#pragma unroll
  for (int mt = 0; mt < 2; ++mt)
#pragma unroll
    for (int r = 0; r < 4; ++r) {
      int row = row0 + mt * 16 + quad * 4 + r;
      int rowc = row < NN ? row : NN - 1;
#pragma unroll
      for (int nt = 0; nt < 2; ++nt)
        ov[mt][nt][r] = h[rowc * 128 + cols[nt]] + acc2[mt][nt][r] + bb2[nt];
    }
#pragma unroll
  for (int mt = 0; mt < 2; ++mt)
#pragma unroll
    for (int r = 0; r < 4; ++r) {
      float q = ov[mt][0][r] * ov[mt][0][r] + ov[mt][1][r] * ov[mt][1][r];
      q += __shfl_xor(q, 1); q += __shfl_xor(q, 2);
      q += __shfl_xor(q, 4); q += __shfl_xor(q, 8);
      if (l16 == 0) red[w][mt * 16 + quad * 4 + r] = q;
    }
  __syncthreads();
#pragma unroll
  for (int mt = 0; mt < 2; ++mt)
#pragma unroll
    for (int r = 0; r < 4; ++r) {
      int rl = mt * 16 + quad * 4 + r;
      float tot = red[0][rl] + red[1][rl] + red[2][rl] + red[3][rl];
      float rr = rsqrtf(tot * (1.f / 128.f) + RMS_EPS);
      int row = row0 + rl;
      if (row < NN) {
        out[row * 128 + cols[0]] = ov[mt][0][r] * rr * wn[0];
        out[row * 128 + cols[1]] = ov[mt][1][r] * rr * wn[1];
      }
    }
}

// ---------------- launch ----------------
extern "C" void kernel_launch(void* const* d_in, const int* in_sizes, int n_in,
                              void* d_out, int out_size, void* d_ws, size_t ws_size,
                              hipStream_t stream) {
  const float* x   = (const float*)d_in[0];
  const int*   ei  = (const int*)d_in[1];
  const float* ea  = (const float*)d_in[2];
  const float* Wl  = (const float*)d_in[3];
  const float* bl  = (const float*)d_in[4];
  const float* Wr  = (const float*)d_in[5];
  const float* br  = (const float*)d_in[6];
  const float* We  = (const float*)d_in[7];
  const float* att = (const float*)d_in[8];
  const float* bg  = (const float*)d_in[9];
  const float* wn1 = (const float*)d_in[10];
  const float* wn2 = (const float*)d_in[11];
  const float* W1  = (const float*)d_in[12];
  const float* b1  = (const float*)d_in[13];
  const float* W2  = (const float*)d_in[14];
  const float* b2  = (const float*)d_in[15];

  float* wsf = (float*)d_ws;
  int*   wsi = (int*)d_ws;

  float* gat  = wsf + OFF_GAT;
  u16* xlb    = (u16*)(wsf + OFF_XLB);
  u16* xrb    = (u16*)(wsf + OFF_XRB);
  int2* se    = (int2*)(wsf + OFF_SE);
  int* cnt    = wsi + OFF_CNT;
  int* pos    = wsi + OFF_CNT;   // alias: scan rebuilds in-place as cursors
  int* offs   = wsi + OFF_OFS;
  float* hbuf = wsf + OFF_H;     // aliases xlb+xrb (dead after k2)
  u16* wlrt   = (u16*)(wsf + OFF_WLRT);
  u16* w1t    = (u16*)(wsf + OFF_W1T);
  u16* w2t    = (u16*)(wsf + OFF_W2T);

  // fused prep (zero hist + weight transposes)
  k_prep<<<256, 256, 0, stream>>>(Wl, Wr, W1, W2, cnt, wlrt, w1t, w2t);

  // CSR structure
  k_hist<<<(EE + 255) / 256, 256, 0, stream>>>(ei, cnt);
  k_scan<<<1, 1024, 0, stream>>>(cnt, offs, pos);
  k_permute<<<(EE + 255) / 256, 256, 0, stream>>>(ei, pos, se);

  // node transforms (MFMA) -> bf16
  k1_mfma<<<(NN + 31) / 32, 256, 0, stream>>>(x, wlrt, bl, br, xlb, xrb);

  // fused logits + batched online softmax + weighted accumulation
  k2_attn<<<2048, 256, 0, stream>>>(offs, se, ea, att, We, xlb, xrb, gat);

  // norm1
  k5_norm1<<<NN / 4, 256, 0, stream>>>(x, gat, bg, wn1, hbuf);

  // fused FFN (MFMA) + residual + norm2
  k6_mfma<<<(NN + 31) / 32, 256, 0, stream>>>(hbuf, w1t, w2t, b1, b2, wn2, (float*)d_out);
}